// Round 5
// baseline (112.515 us; speedup 1.0000x reference)
//
#include <hip/hip_runtime.h>

#define PL 128
#define STRIDE 64
#define WSZ 16

typedef float f32x4 __attribute__((ext_vector_type(4)));

// Fused, single-dispatch. Part C reproduces the fill-kernel's access pattern:
// a device-wide linear grid-stride sweep (one moving contiguous window) instead
// of per-block streams, to get DRAM row-buffer locality per channel.
//
// Register-broadcast invariant: adjs is [P][4096] f32x4, 4096 per patch.
// With T = gridDim.x*256 f32x4 stride and gridDim.x % 16 == 1:
//   q = m & 4095 satisfies  q & 255 == tid  (always)
//   and (q >> 8) increments by 1 mod 16 each grid-stride step.
// So each thread only ever stores 16 distinct f32x4 values; unroll by 16 keeps
// all v[i] indices static. Block rotation r = bid & 15 aligns v[i] with the
// chunk index (r + i) & 15.
__global__ __launch_bounds__(256) void fused_kernel(
    const float* __restrict__ I, const float* __restrict__ Q,
    const float* __restrict__ ew, float* __restrict__ out, int P)
{
    const int tid = threadIdx.x;
    const int bid = blockIdx.x;
    const unsigned T = gridDim.x * 256;          // grid-stride in f32x4 units
    const unsigned idx0 = bid * 256 + tid;

    // ---- Part A: patches [P,128,2] (8 MB, ~1.5% of traffic) ----
    {
        f32x4* pout = reinterpret_cast<f32x4*>(out);
        const unsigned total = (unsigned)P * (PL / 2);   // one f32x4 covers t,t+1
        for (unsigned idx = idx0; idx < total; idx += T) {
            int p = (int)(idx >> 6);
            int t = ((int)idx & 63) * 2;
            int src = p * STRIDE + t;
            f32x4 val = {I[src], Q[src], I[src + 1], Q[src + 1]};
            __builtin_nontemporal_store(val, &pout[idx]);
        }
    }

    // ---- Part B: 16 f32x4 adj fragments, rotated by r = bid & 15 ----
    const int r = bid & 15;
    f32x4 v[16];
#pragma unroll
    for (int i = 0; i < 16; ++i) {
        const int kk  = (r + i) & 15;            // chunk this slot will store
        const int row = kk * 8 + (tid >> 5);
        const int j0  = (tid & 31) * 4;
        f32x4 val = {0.f, 0.f, 0.f, 0.f};
#pragma unroll
        for (int c = 0; c < 4; ++c) {
            int j = j0 + c;
            int d = row - j; if (d < 0) d = -d;
            if (d > 0 && d <= WSZ) {
                val[c] = 1.0f / (1.0f + __expf(-ew[row * PL + j]));
            }
        }
        v[i] = val;
    }

    // ---- Part C: device-wide linear sweep over adjs [P*4096 f32x4] ----
    f32x4* aout = reinterpret_cast<f32x4*>(out + (size_t)P * PL * 2);
    const unsigned M = (unsigned)P * (PL * PL / 4);      // 31,993,856 for P=7811
    unsigned m = idx0;

    // full unrolled blocks: all 16 stores in-bounds
    const long long lim = (long long)M - 15LL * T;
    while ((long long)m < lim) {
#pragma unroll
        for (int i = 0; i < 16; ++i) {
            __builtin_nontemporal_store(v[i], &aout[m]);
            m += T;
        }
    }
    // tail: per-store bounds check, same static unroll
    while (m < M) {
#pragma unroll
        for (int i = 0; i < 16; ++i) {
            if (m < M) __builtin_nontemporal_store(v[i], &aout[m]);
            m += T;
        }
    }
}

extern "C" void kernel_launch(void* const* d_in, const int* in_sizes, int n_in,
                              void* d_out, int out_size, void* d_ws, size_t ws_size,
                              hipStream_t stream) {
    const float* I  = (const float*)d_in[0];
    const float* Q  = (const float*)d_in[1];
    const float* ew = (const float*)d_in[2];
    float* out = (float*)d_out;

    const int n = in_sizes[0];
    const int P = (n - PL) / STRIDE + 1;   // 7811 for L=500000

    // gridB % 16 == 1 (invariant above); 1009 blocks * 4 waves fit co-resident
    // at ~90 VGPR (4 waves/SIMD) so the sweep window stays coherent.
    const int gridB = 1009;
    fused_kernel<<<gridB, 256, 0, stream>>>(I, Q, ew, out, P);
}

// Round 6
// 106.098 us; speedup vs baseline: 1.0605x; 1.0605x over previous
//
#include <hip/hip_runtime.h>

#define PL 128
#define STRIDE 64
#define WSZ 16

typedef float f32x4 __attribute__((ext_vector_type(4)));

// Fused, single-dispatch.
// Part C: block b owns patches [4b,4b+4). Within a patch, wave w owns the
// contiguous 16 KB span [w*16KB, (w+1)*16KB) and writes it as 16 CONSECUTIVE
// 1 KB store instructions (dst[u*64], u=0..15) — per-wave sequential bursts,
// matching the fill-kernel's DRAM-friendly stream shape (previous variants'
// waves jumped 4KB..4MB between consecutive stores).
//
// Register mapping for the span: f32x4 index within patch = w*1024 + u*64 + lane
//   -> element  e = w*4096 + u*256 + lane*4 + c
//   -> row i = w*32 + u*2 + (lane>>5),  col j = (lane&31)*4 + c
// so v[u] (16 f32x4 = 64 VGPR) covers the whole span, all indices static.
__global__ __launch_bounds__(256) void fused_kernel(
    const float* __restrict__ I, const float* __restrict__ Q,
    const float* __restrict__ ew, float* __restrict__ out, int P)
{
    const int tid  = threadIdx.x;
    const int bid  = blockIdx.x;
    const int nblk = gridDim.x;
    const int lane = tid & 63;
    const int w    = tid >> 6;            // wave id 0..3

    // ---- Part A: patches [P,128,2] (8 MB) ----
    {
        f32x4* pout = reinterpret_cast<f32x4*>(out);
        const int total = P * (PL / 2);   // one f32x4 covers t, t+1
        for (int idx = bid * 256 + tid; idx < total; idx += nblk * 256) {
            int p = idx >> 6;
            int t = (idx & 63) * 2;
            int src = p * STRIDE + t;
            f32x4 val = {I[src], Q[src], I[src + 1], Q[src + 1]};
            __builtin_nontemporal_store(val, &pout[idx]);
        }
    }

    // ---- Part B: this wave-span's 64 adj elements -> 16 f32x4 registers ----
    f32x4 v[16];
    const int rbase = w * 32 + (lane >> 5);
    const int j0    = (lane & 31) * 4;
#pragma unroll
    for (int u = 0; u < 16; ++u) {
        const int row = rbase + u * 2;
        f32x4 val = {0.f, 0.f, 0.f, 0.f};
#pragma unroll
        for (int c = 0; c < 4; ++c) {
            int j = j0 + c;
            int d = row - j; if (d < 0) d = -d;
            if (d > 0 && d <= WSZ) {
                val[c] = 1.0f / (1.0f + __expf(-ew[row * PL + j]));
            }
        }
        v[u] = val;
    }

    // ---- Part C: store-only broadcast, wave-contiguous 16 KB bursts ----
    f32x4* aout = reinterpret_cast<f32x4*>(out + (size_t)P * PL * 2);
    int p0 = bid * 4;
    int p1 = p0 + 4; if (p1 > P) p1 = P;
    for (int p = p0; p < p1; ++p) {
        f32x4* dst = aout + (size_t)p * (PL * PL / 4) + w * 1024 + lane;
#pragma unroll
        for (int u = 0; u < 16; ++u) {
            __builtin_nontemporal_store(v[u], &dst[u * 64]);
        }
    }
}

extern "C" void kernel_launch(void* const* d_in, const int* in_sizes, int n_in,
                              void* d_out, int out_size, void* d_ws, size_t ws_size,
                              hipStream_t stream) {
    const float* I  = (const float*)d_in[0];
    const float* Q  = (const float*)d_in[1];
    const float* ew = (const float*)d_in[2];
    float* out = (float*)d_out;

    const int n = in_sizes[0];
    const int P = (n - PL) / STRIDE + 1;   // 7811 for L=500000

    const int nblk = (P + 3) / 4;          // block b -> patches [4b, 4b+4)
    fused_kernel<<<nblk, 256, 0, stream>>>(I, Q, ew, out, P);
}